// Round 10
// baseline (793.877 us; speedup 1.0000x reference)
//
#include <hip/hip_runtime.h>
#include <hip/hip_bf16.h>
#include <math.h>

#define H 64
#define DM 128
#define GDIM 192      // 3*H
#define BSZ 32
#define SEQ 500
#define NROW (BSZ*SEQ)  // 16000
#define LIBN 2145
#define FFD 128
#define NKC2 75       // padded grouped-K chunks of 32 (2400 slots, 300 groups)
#define NGRP 300
#define CPK2 153600   // NKC2*4*64*8 shorts per layer
#define PSTR 196      // part row-block stride (192 + 4 pad: kills 4-way qq bank conflict)

typedef __attribute__((ext_vector_type(8))) short short8;   // bf16x8 MFMA operand
typedef __attribute__((ext_vector_type(4))) float f32x4;    // MFMA accumulator
typedef __attribute__((ext_vector_type(2))) float f32x2;    // packed-math pair
typedef __attribute__((ext_vector_type(4))) unsigned u32x4;

__device__ __forceinline__ float sigf(float x) {
    return 1.0f / (1.0f + __expf(-x));
}
__device__ __forceinline__ float tanhfast(float x) {
    x = fminf(fmaxf(x, -15.0f), 15.0f);
    float t = __expf(-2.0f * x);
    return (1.0f - t) / (1.0f + t);
}
__device__ __forceinline__ short bf16r(float f) {   // fp32 -> bf16 rne
    unsigned u = __float_as_uint(f);
    unsigned r = (u + 0x7fffu + ((u >> 16) & 1u)) >> 16;
    return (short)r;
}
// packed dual-FMA: d.lo = a.lo*b.lo + c.lo, d.hi = a.hi*b.hi + c.hi (1 inst vs 2)
__device__ __forceinline__ f32x2 pkfma(f32x2 a, f32x2 b, f32x2 c) {
    f32x2 d;
    asm("v_pk_fma_f32 %0, %1, %2, %3" : "=v"(d) : "v"(a), "v"(b), "v"(c));
    return d;
}

// lgkm-only barrier: xp prefetch loads / hbuf stores stay in flight (correctness-
// proven in R1; all cross-wave data here is LDS -> lgkm ordering is sufficient).
#define BAR_LGKM() asm volatile("s_waitcnt lgkmcnt(0)\n\ts_barrier" ::: "memory")

// decode grouped-K group id -> (a, b): af[j] = z[a] * z[b + j], j = 0..7
__device__ __forceinline__ void grp_decode(int g, int& a, int& b) {
    if (g < 8) { a = 64; b = g * 8; }                 // linear: 1 * z[8g..8g+7]
    else if (g == 8 || g >= 297) { a = 64; b = 64; }  // const slot / padding
    else {
        int G = g - 9, acc = 0;
        a = 0; b = 0;
        for (int i2 = 0; i2 < 64; i2++) {
            int cnt = 8 - (i2 >> 3);                  // aligned 8-groups covering [i2,63]
            if (G < acc + cnt) { a = i2; b = ((i2 >> 3) + (G - acc)) * 8; break; }
            acc += cnt;
        }
    }
}

// ---------------- ONE fused pack kernel (unchanged from R9) --------------------------
__global__ void pack_all(const float* __restrict__ wih0,
                         const float* __restrict__ coeffs,
                         const float* __restrict__ w1,
                         const float* __restrict__ w2,
                         float* __restrict__ wtp,
                         short* __restrict__ bfa) {
    int idx = blockIdx.x * 256 + threadIdx.x;        // grid covers exactly 364544
    if (idx < GDIM * DM) {                           // ---- wih0 -> wt2 (k-major) ----
        int k = idx / GDIM;
        int g = idx - k * GDIM;
        wtp[idx] = wih0[g * DM + k];
        return;
    }
    int r = idx - GDIM * DM;
    int l = r / (CPK2 + 2 * 8192);
    int q = r % (CPK2 + 2 * 8192);
    if (q < CPK2) {                                  // ---- coef (grouped-K) ----
        const float* coef = coeffs + (size_t)l * LIBN * H;
        int j = q & 7, lane = (q >> 3) & 63, nt = (q >> 9) & 3, kc = q >> 11;
        int grp = kc * 4 + (lane >> 4);
        int row = -1;
        if (grp < 8) row = 1 + grp * 8 + j;
        else if (grp == 8) row = (j == 0) ? 0 : -1;
        else if (grp < 297) {
            int a, b;
            grp_decode(grp, a, b);
            int jdx = b + j;
            if (jdx >= a) row = 65 + a * 64 - (a * (a - 1)) / 2 + (jdx - a);
        }
        int c = nt * 16 + (lane & 15);
        bfa[(size_t)l * CPK2 + q] = (row >= 0) ? bf16r(coef[(size_t)row * H + c]) : (short)0;
        return;
    }
    int q2 = q - CPK2;
    if (q2 < 8192) {                                 // ---- W1^T fragments ----
        const float* w1l = w1 + (size_t)l * FFD * H;
        int j = q2 & 7, lane = (q2 >> 3) & 63, nt = (q2 >> 9) & 7, kc = q2 >> 12;
        int k = kc * 32 + ((lane >> 4) << 3) + j;
        int n = nt * 16 + (lane & 15);
        bfa[(size_t)2 * CPK2 + l * 8192 + q2] = bf16r(w1l[(size_t)n * H + k]);
        return;
    }
    int q3 = q2 - 8192;                              // ---- W2^T fragments ----
    const float* w2l = w2 + (size_t)l * H * FFD;
    int j = q3 & 7, lane = (q3 >> 3) & 63, nt = (q3 >> 9) & 3, kc = q3 >> 11;
    int k = kc * 32 + ((lane >> 4) << 3) + j;
    int n = nt * 16 + (lane & 15);
    bfa[(size_t)2 * CPK2 + 2 * 8192 + l * 8192 + q3] = bf16r(w2l[(size_t)n * FFD + k]);
}

// ---------------- xp0 = x @ Wih0^T + bih0: register-tiled (R9, −45 µs, FROZEN) -------
__global__ __launch_bounds__(256, 1) void xp0_gemm(const float* __restrict__ x,
                                                   const float* __restrict__ wt2,
                                                   const float* __restrict__ bih0,
                                                   float* __restrict__ xpT) {
    __shared__ __align__(16) float wlds[DM * GDIM];   // 128 x 192 k-major, 96 KB
    int tid = threadIdx.x;
    int wv = __builtin_amdgcn_readfirstlane(tid >> 6);
    int lane = tid & 63;

    for (int p = tid; p < DM * GDIM / 4; p += 256)    // stage W^T: coalesced, one-time
        ((f32x4*)wlds)[p] = ((const f32x4*)wt2)[p];

    int i = lane >> 2;                                // row group 0..15
    int j = lane & 3;                                 // col group 0..3
    int rb = blockIdx.x * 64;
    int row0 = rb + 4 * i;

    f32x4 acc[3][4];
#pragma unroll
    for (int t = 0; t < 3; t++) {
        f32x4 bv = *(const f32x4*)(bih0 + 16 * (wv + 4 * t) + 4 * j);
#pragma unroll
        for (int ii = 0; ii < 4; ii++) acc[t][ii] = bv;
    }
    __syncthreads();

    const float* xr0 = x + (size_t)row0 * DM;
    for (int k4 = 0; k4 < 32; k4++) {
        f32x4 xr[4];
#pragma unroll
        for (int ii = 0; ii < 4; ii++)
            xr[ii] = *(const f32x4*)(xr0 + ii * DM + k4 * 4);
#pragma unroll
        for (int t = 0; t < 3; t++) {
            int cb = 16 * (wv + 4 * t);
#pragma unroll
            for (int e = 0; e < 4; e++) {
                f32x4 wvv = *(const f32x4*)&wlds[(k4 * 4 + e) * GDIM + cb + 4 * j];
#pragma unroll
                for (int ii = 0; ii < 4; ii++)
                    acc[t][ii] += wvv * xr[ii][e];
            }
        }
    }
    int bb = row0 / 500;
    int ss = row0 - bb * 500;
    float* base = xpT + ((size_t)(bb * 125 + (ss >> 2)) * GDIM) * 4;
#pragma unroll
    for (int t = 0; t < 3; t++) {
        int cb = 16 * (wv + 4 * t);
#pragma unroll
        for (int jj = 0; jj < 4; jj++) {
            int g = cb + 4 * j + jj;
            f32x4 v = { acc[t][0][jj], acc[t][1][jj], acc[t][2][jj], acc[t][3][jj] };
            *(f32x4*)(base + (size_t)g * 4) = v;
        }
    }
}

// ---------------- fused 2-layer GRU scan: ONE-barrier redundant-gate structure -------
// 12 waves (m = wv%3, q = wv/3) as R7, but phase 2 is ELIMINATED: after the single
// lgkm barrier each wave gate-computes its OWN 16-element h-slice redundantly
// (4 lanes/element: 3 part reads + shfl_xor qq-reduce + gate chain), keeps h in
// registers (h never touches LDS), redistributes within-wave via uniform-lane __shfl
// (-> readlane/SGPR broadcast), then runs the R7 pkfma matvec into double-buffered
// part[]. One barrier/step (was 2 with a serial 2-wave gate tail).
//   iteration u: m<=1 waves compute h0[u] (u<500) and part[u&1][m] = W@h0[u];
//   m==2 waves compute h1[u-1] (u>=1) from part[(u-1)&1][1,2], and
//   part[u&1][2] = Whh1@h1[u-1]. u = 0..500.
// part stride PSTR=196: qq-stride 192%32==0 was a 4-way bank conflict on gate reads.
__global__ __launch_bounds__(768, 3) void gru_fused(const float* __restrict__ xpT,
                                                    const float* __restrict__ whh0,
                                                    const float* __restrict__ bhh0,
                                                    const float* __restrict__ wih1,
                                                    const float* __restrict__ bih1,
                                                    const float* __restrict__ whh1,
                                                    const float* __restrict__ bhh1,
                                                    float* __restrict__ hbuf) {
    int b = blockIdx.x;
    int tid = threadIdx.x;
    int wv = __builtin_amdgcn_readfirstlane(tid >> 6);
    int lane = tid & 63;
    int m = wv % 3;
    int q = wv / 3;
    int k0 = q * 16;
    int kel = k0 + (lane >> 2);    // element this lane gate-computes (4-redundant)
    int qq = lane & 3;             // which writer-q partial this lane reads

    __shared__ float part[2][3][4][PSTR];   // [buf][m][writer-q][gate*64+row (+pad)]

    for (int i = tid; i < 2 * 3 * 4 * PSTR; i += 768)
        ((float*)part)[i] = 0.0f;

    const float* W = (m == 0) ? whh0 : (m == 1) ? wih1 : whh1;
    f32x2 wrp[8], wzp[8], wnp[8];          // R7-proven resident weight layout
#pragma unroll
    for (int k4 = 0; k4 < 4; k4++) {
        f32x4 a = ((const f32x4*)(W + (size_t)lane * H + k0))[k4];
        f32x4 c = ((const f32x4*)(W + (size_t)(H + lane) * H + k0))[k4];
        f32x4 d = ((const f32x4*)(W + (size_t)(2 * H + lane) * H + k0))[k4];
        wrp[2*k4]   = __builtin_shufflevector(a, a, 0, 1);
        wrp[2*k4+1] = __builtin_shufflevector(a, a, 2, 3);
        wzp[2*k4]   = __builtin_shufflevector(c, c, 0, 1);
        wzp[2*k4+1] = __builtin_shufflevector(c, c, 2, 3);
        wnp[2*k4]   = __builtin_shufflevector(d, d, 0, 1);
        wnp[2*k4+1] = __builtin_shufflevector(d, d, 2, 3);
    }

    // per-lane gate biases for element kel
    float br, bz, bn, cr = 0.f, cz = 0.f, cn = 0.f;
    if (m <= 1) {
        br = bhh0[kel]; bz = bhh0[H + kel]; bn = bhh0[2 * H + kel];
    } else {
        br = bih1[kel]; bz = bih1[H + kel]; bn = bih1[2 * H + kel];
        cr = bhh1[kel]; cz = bhh1[H + kel]; cn = bhh1[2 * H + kel];
    }

    float hprev = 0.0f;    // this lane's element state (h0 for m<=1, h1 for m==2)
    float hbv = 0.0f;      // m==2: buffered h1 for this lane's time slot (t&3 == qq)
    f32x4 xq[4][3];        // xp ring: this lane's element, gates r/z/n, e=0..3
#pragma unroll
    for (int s = 0; s < 4; s++)
#pragma unroll
        for (int g = 0; g < 3; g++) xq[s][g] = (f32x4){0.f, 0.f, 0.f, 0.f};
    const float* xpB = xpT + (size_t)b * 125 * GDIM * 4;

    auto pre = [&](int c, int slot) {
        if (m <= 1 && c < 125) {
            xq[slot][0] = *(const f32x4*)(xpB + ((size_t)c * GDIM + kel) * 4);
            xq[slot][1] = *(const f32x4*)(xpB + ((size_t)c * GDIM + 64 + kel) * 4);
            xq[slot][2] = *(const f32x4*)(xpB + ((size_t)c * GDIM + 128 + kel) * 4);
        }
    };
    pre(0, 0);
    pre(1, 1);
    __syncthreads();

    // e = u&3 compile-time at each call site; slot = chunk&3 compile-time.
    auto step = [&](int u, int e, int slot) {
        BAR_LGKM();                            // prev parts visible; ONE barrier/step
        int rd = (e + 1) & 1;                  // (u-1)&1
        float hnew = hprev;
        if (m <= 1) {
            if (u < SEQ) {
                float pr = part[rd][0][qq][kel];
                float pz = part[rd][0][qq][H + kel];
                float pn = part[rd][0][qq][2 * H + kel];
                pr += __shfl_xor(pr, 1); pr += __shfl_xor(pr, 2);
                pz += __shfl_xor(pz, 1); pz += __shfl_xor(pz, 2);
                pn += __shfl_xor(pn, 1); pn += __shfl_xor(pn, 2);
                float rg = sigf(xq[slot][0][e] + pr + br);
                float zg = sigf(xq[slot][1][e] + pz + bz);
                float ng = tanhfast(xq[slot][2][e] + rg * (pn + bn));
                hnew = (1.0f - zg) * ng + zg * hprev;
                hprev = hnew;
            }
        } else {
            if (u >= 1) {
                float ar = part[rd][1][qq][kel];
                float az = part[rd][1][qq][H + kel];
                float an = part[rd][1][qq][2 * H + kel];
                float gr = part[rd][2][qq][kel];
                float gz = part[rd][2][qq][H + kel];
                float gn = part[rd][2][qq][2 * H + kel];
                ar += __shfl_xor(ar, 1); ar += __shfl_xor(ar, 2);
                az += __shfl_xor(az, 1); az += __shfl_xor(az, 2);
                an += __shfl_xor(an, 1); an += __shfl_xor(an, 2);
                gr += __shfl_xor(gr, 1); gr += __shfl_xor(gr, 2);
                gz += __shfl_xor(gz, 1); gz += __shfl_xor(gz, 2);
                gn += __shfl_xor(gn, 1); gn += __shfl_xor(gn, 2);
                float rg = sigf((ar + br) + (gr + cr));
                float zg = sigf((az + bz) + (gz + cz));
                float ng = tanhfast((an + bn) + rg * (gn + cn));
                hnew = (1.0f - zg) * ng + zg * hprev;     // h1[u-1]
                hprev = hnew;
                if (((e + 3) & 3) == qq) hbv = hnew;      // time (u-1), slot qq
                if (e == 0 && u >= 4)                     // flush times u-4..u-1
                    hbuf[((size_t)b * SEQ + (u - 4) + qq) * H + kel] = hbv;
            }
        }
        // matvec into part[e&1]: redistribute own h-slice within-wave, then pkfma
        if (m == 2 || u < SEQ) {
            f32x2 hp[8];
#pragma unroll
            for (int t = 0; t < 8; t++) {
                hp[t][0] = __shfl(hnew, 8 * t);           // h[k0+2t]   (lane 8t)
                hp[t][1] = __shfl(hnew, 8 * t + 4);       // h[k0+2t+1] (lane 8t+4)
            }
            f32x2 arp = {0.f, 0.f}, azp = {0.f, 0.f}, anp = {0.f, 0.f};
#pragma unroll
            for (int t = 0; t < 8; t++) {
                arp = pkfma(wrp[t], hp[t], arp);
                azp = pkfma(wzp[t], hp[t], azp);
                anp = pkfma(wnp[t], hp[t], anp);
            }
            int wb = e & 1;
            part[wb][m][q][lane]         = arp[0] + arp[1];
            part[wb][m][q][H + lane]     = azp[0] + azp[1];
            part[wb][m][q][2 * H + lane] = anp[0] + anp[1];
        }
    };

    for (int scb = 0; scb < 31; scb++) {
#pragma unroll
        for (int sci = 0; sci < 4; sci++) {
            int sc = scb * 4 + sci;
            if ((sci & 1) == 0) {
                pre(sc + 2, (sci + 2) & 3);
                pre(sc + 3, (sci + 3) & 3);
            }
            int s0 = sc * 4;
            step(s0 + 0, 0, sci);
            step(s0 + 1, 1, sci);
            step(s0 + 2, 2, sci);
            step(s0 + 3, 3, sci);
        }
    }
    {   // sc = 124 (slot 0, prefetched at scb=30/sci=2): steps 496..499
        step(496, 0, 0);
        step(497, 1, 0);
        step(498, 2, 0);
        step(499, 3, 0);
    }
    // tail u = 500: m==2 computes h1[499] and flushes times 496..499
    step(500, 0, 0);
}

// ---------------- FUSED 2-layer SINDy kernel + parallel LN (R8, FROZEN) --------------
__global__ __launch_bounds__(512) void sindy_fused(const float* __restrict__ hbuf_in,
                                                   const short* __restrict__ bfa,
                                                   const float* __restrict__ ln1g,
                                                   const float* __restrict__ ln1b,
                                                   const float* __restrict__ b1g,
                                                   const float* __restrict__ b2g,
                                                   const float* __restrict__ ln2g,
                                                   const float* __restrict__ ln2b,
                                                   float* __restrict__ out) {
    __shared__ float z[65 * 68];                   // row 64 = zero pad (safe b-reads)
    __shared__ float upd[64 * 68];
    __shared__ float ff[64 * 132];
    __shared__ unsigned kmap2[NGRP];
    __shared__ float bfs1[2][FFD], bfs2[2][H];
    __shared__ float g1s[2][H], b1s[2][H], g2s[2][H], b2s[2][H];

    int tid = threadIdx.x;
    int wv = __builtin_amdgcn_readfirstlane(tid >> 6);
    int lane = tid & 63;
    int row0 = blockIdx.x * 64;

    for (int idx = tid; idx < 64 * 16; idx += 512) {
        int r = idx >> 4, c4 = idx & 15;
        *(f32x4*)&z[r * 68 + c4 * 4] = *(const f32x4*)&hbuf_in[(size_t)(row0 + r) * H + c4 * 4];
    }
    for (int idx = tid; idx < 64 * 17; idx += 512)
        *(f32x4*)&upd[idx * 4] = (f32x4){0.f, 0.f, 0.f, 0.f};
    if (tid < 64) {
        z[tid * 68 + 64] = 1.0f; z[tid * 68 + 65] = 0.0f;
        z[tid * 68 + 66] = 0.0f; z[tid * 68 + 67] = 0.0f;
    }
    if (tid < 68) z[64 * 68 + tid] = 0.0f;         // zero pad row
    if (tid < NGRP) {
        int a, b;
        grp_decode(tid, a, b);
        kmap2[tid] = ((unsigned)a << 16) | (unsigned)b;
    }
    if (tid < FFD) { bfs1[0][tid] = b1g[tid]; bfs1[1][tid] = b1g[FFD + tid]; }
    if (tid < H) {
        bfs2[0][tid] = b2g[tid];      bfs2[1][tid] = b2g[H + tid];
        g1s[0][tid] = ln1g[tid];      g1s[1][tid] = ln1g[H + tid];
        b1s[0][tid] = ln1b[tid];      b1s[1][tid] = ln1b[H + tid];
        g2s[0][tid] = ln2g[tid];      g2s[1][tid] = ln2g[H + tid];
        b2s[0][tid] = ln2b[tid];      b2s[1][tid] = ln2b[H + tid];
    }
    __syncthreads();

    int kj0 = ((lane >> 4) << 3);
    int m0 = (wv & 3) * 16;
    int m = m0 + (lane & 15);
    int rbase = m0 + ((lane >> 4) << 2);
    int cb16 = lane & 15;
    const float* zrow = &z[m * 68];
    int lrow = tid >> 3;                           // parallel-LN: row, 8 threads/row
    int lk = (tid & 7) * 8;                        // this thread's 8-col slice

#pragma unroll
    for (int l = 0; l < 2; l++) {
        const short* cpk = bfa + (size_t)l * CPK2;
        const short* w1p = bfa + (size_t)2 * CPK2 + l * 8192;
        const short* w2p = bfa + (size_t)2 * CPK2 + 2 * 8192 + l * 8192;

        // ---- phase 1: upd = theta @ coef (grouped-K, k-split 2-way) ----
        {
            int p = wv >> 2;
            f32x4 acc[4] = {{0,0,0,0},{0,0,0,0},{0,0,0,0},{0,0,0,0}};
            for (int kc = p; kc < NKC2; kc += 2) {
                unsigned ab = kmap2[kc * 4 + (lane >> 4)];
                float za = zrow[ab >> 16];
                const float* zb = &zrow[ab & 0xffffu];
                f32x4 z0 = *(const f32x4*)zb;
                f32x4 z1 = *(const f32x4*)(zb + 4);
                short8 af;
                af[0] = bf16r(za * z0[0]);
                af[1] = bf16r(za * z0[1]);
                af[2] = bf16r(za * z0[2]);
                af[3] = bf16r(za * z0[3]);
                af[4] = bf16r(za * z1[0]);
                af[5] = bf16r(za * z1[1]);
                af[6] = bf16r(za * z1[2]);
                af[7] = bf16r(za * z1[3]);
                const short* cb = cpk + ((size_t)(kc * 4) * 64 + lane) * 8;
#pragma unroll
                for (int nt = 0; nt < 4; nt++) {
                    short8 bf = *(const short8*)(cb + (size_t)nt * 512);
                    acc[nt] = __builtin_amdgcn_mfma_f32_16x16x32_bf16(af, bf, acc[nt], 0, 0, 0);
                }
            }
#pragma unroll
            for (int nt = 0; nt < 4; nt++)
#pragma unroll
                for (int r = 0; r < 4; r++)
                    atomicAdd(&upd[(rbase + r) * 68 + nt * 16 + cb16], acc[nt][r]);
        }
        __syncthreads();

        // ---- LN1 (all 512 threads, 8/row) -> z ----
        {
            float v[8];
            float s1 = 0.0f;
#pragma unroll
            for (int i = 0; i < 8; i++) {
                v[i] = z[lrow * 68 + lk + i] + upd[lrow * 68 + lk + i];
                s1 += v[i];
            }
            s1 += __shfl_xor(s1, 1); s1 += __shfl_xor(s1, 2); s1 += __shfl_xor(s1, 4);
            float mn = s1 * (1.0f / 64.0f);
            float s2 = 0.0f;
#pragma unroll
            for (int i = 0; i < 8; i++) { float d = v[i] - mn; s2 += d * d; }
            s2 += __shfl_xor(s2, 1); s2 += __shfl_xor(s2, 2); s2 += __shfl_xor(s2, 4);
            float rstd = 1.0f / sqrtf(s2 * (1.0f / 64.0f) + 1e-5f);
#pragma unroll
            for (int i = 0; i < 8; i++)
                z[lrow * 68 + lk + i] = (v[i] - mn) * rstd * g1s[l][lk + i] + b1s[l][lk + i];
        }
        __syncthreads();

        // ---- phase 3: ff = gelu(LN1 @ W1^T + b1) ----
        {
            int nq = wv >> 2;
            f32x4 acc[4] = {{0,0,0,0},{0,0,0,0},{0,0,0,0},{0,0,0,0}};
#pragma unroll
            for (int kc = 0; kc < 2; kc++) {
                f32x4 za = *(const f32x4*)&z[m * 68 + kc * 32 + kj0];
                f32x4 zb = *(const f32x4*)&z[m * 68 + kc * 32 + kj0 + 4];
                short8 af;
                af[0] = bf16r(za[0]); af[1] = bf16r(za[1]); af[2] = bf16r(za[2]); af[3] = bf16r(za[3]);
                af[4] = bf16r(zb[0]); af[5] = bf16r(zb[1]); af[6] = bf16r(zb[2]); af[7] = bf16r(zb[3]);
#pragma unroll
                for (int t = 0; t < 4; t++) {
                    int nt = nq * 4 + t;
                    short8 bf = *(const short8*)(w1p + ((size_t)(kc * 8 + nt) * 64 + lane) * 8);
                    acc[t] = __builtin_amdgcn_mfma_f32_16x16x32_bf16(af, bf, acc[t], 0, 0, 0);
                }
            }
#pragma unroll
            for (int t = 0; t < 4; t++) {
                int col = (nq * 4 + t) * 16 + cb16;
#pragma unroll
                for (int r = 0; r < 4; r++) {
                    float v = acc[t][r] + bfs1[l][col];
                    ff[(rbase + r) * 132 + col] = 0.5f * v * (1.0f + erff(v * 0.70710678118654752f));
                }
            }
        }
        __syncthreads();

        // ---- phase 5: upd = ff @ W2^T + b2 (plain stores, full overwrite) ----
        {
            int nh = wv >> 2;
            f32x4 acc[2] = {{0,0,0,0},{0,0,0,0}};
            const float* frow = &ff[m * 132];
#pragma unroll
            for (int kc = 0; kc < 4; kc++) {
                f32x4 fa = *(const f32x4*)&frow[kc * 32 + kj0];
                f32x4 fb = *(const f32x4*)&frow[kc * 32 + kj0 + 4];
                short8 af;
                af[0] = bf16r(fa[0]); af[1] = bf16r(fa[1]); af[2] = bf16r(fa[2]); af[3] = bf16r(fa[3]);
                af[4] = bf16r(fb[0]); af[5] = bf16r(fb[1]); af[6] = bf16r(fb[2]); af[7] = bf16r(fb[3]);
#pragma unroll
                for (int t = 0; t < 2; t++) {
                    int nt = nh * 2 + t;
                    short8 bf = *(const short8*)(w2p + ((size_t)(kc * 4 + nt) * 64 + lane) * 8);
                    acc[t] = __builtin_amdgcn_mfma_f32_16x16x32_bf16(af, bf, acc[t], 0, 0, 0);
                }
            }
#pragma unroll
            for (int t = 0; t < 2; t++) {
                int col = (nh * 2 + t) * 16 + cb16;
#pragma unroll
                for (int r = 0; r < 4; r++)
                    upd[(rbase + r) * 68 + col] = acc[t][r] + bfs2[l][col];
            }
        }
        __syncthreads();

        // ---- LN2 (all 512 threads): l=0 -> z (stay in LDS); l=1 -> out ----
        {
            float v[8];
            float s1 = 0.0f;
#pragma unroll
            for (int i = 0; i < 8; i++) {
                v[i] = z[lrow * 68 + lk + i] + upd[lrow * 68 + lk + i];
                s1 += v[i];
            }
            s1 += __shfl_xor(s1, 1); s1 += __shfl_xor(s1, 2); s1 += __shfl_xor(s1, 4);
            float mn = s1 * (1.0f / 64.0f);
            float s2 = 0.0f;
#pragma unroll
            for (int i = 0; i < 8; i++) { float d = v[i] - mn; s2 += d * d; }
            s2 += __shfl_xor(s2, 1); s2 += __shfl_xor(s2, 2); s2 += __shfl_xor(s2, 4);
            float rstd = 1.0f / sqrtf(s2 * (1.0f / 64.0f) + 1e-5f);
            if (l == 0) {
#pragma unroll
                for (int i = 0; i < 8; i++)
                    z[lrow * 68 + lk + i] = (v[i] - mn) * rstd * g2s[0][lk + i] + b2s[0][lk + i];
            } else {
                int row = row0 + lrow;
                int last = (row % SEQ == SEQ - 1);
#pragma unroll
                for (int i = 0; i < 8; i++) {
                    float res = (v[i] - mn) * rstd * g2s[1][lk + i] + b2s[1][lk + i];
                    out[(size_t)row * H + lk + i] = res;
                    if (last)
                        out[(size_t)NROW * H + (row / SEQ) * H + lk + i] = res;
                }
            }
        }
        __syncthreads();

        if (l == 0) {   // re-zero upd for layer 1's atomicAdd accumulation
            for (int idx = tid; idx < 64 * 17; idx += 512)
                *(f32x4*)&upd[idx * 4] = (f32x4){0.f, 0.f, 0.f, 0.f};
            __syncthreads();
        }
    }
}

extern "C" void kernel_launch(void* const* d_in, const int* in_sizes, int n_in,
                              void* d_out, int out_size, void* d_ws, size_t ws_size,
                              hipStream_t stream) {
    const float* x    = (const float*)d_in[0];
    const float* wih0 = (const float*)d_in[1];
    const float* whh0 = (const float*)d_in[2];
    const float* bih0 = (const float*)d_in[3];
    const float* bhh0 = (const float*)d_in[4];
    const float* wih1 = (const float*)d_in[5];
    const float* whh1 = (const float*)d_in[6];
    const float* bih1 = (const float*)d_in[7];
    const float* bhh1 = (const float*)d_in[8];
    const float* coeffs = (const float*)d_in[9];
    const float* ln1g = (const float*)d_in[10];
    const float* ln1b = (const float*)d_in[11];
    const float* w1   = (const float*)d_in[12];
    const float* b1   = (const float*)d_in[13];
    const float* w2   = (const float*)d_in[14];
    const float* b2   = (const float*)d_in[15];
    const float* ln2g = (const float*)d_in[16];
    const float* ln2b = (const float*)d_in[17];

    float* out = (float*)d_out;
    float* ws  = (float*)d_ws;
    float* xpT = ws;                               // 16000*192 = 3,072,000 floats
    float* wtp = ws + (size_t)NROW * GDIM;         // 24,576 floats (k-major W^T)
    short* bfa = (short*)(wtp + GDIM * DM);        // bf16 fragment area
    float* hbuf = out;                             // reuse first 1,024,000 floats of d_out

    // one fused pack launch: 24576 + 2*(153600+8192+8192) = 364544 = 1424*256
    pack_all<<<1424, 256, 0, stream>>>(wih0, coeffs, w1, w2, wtp, bfa);
    xp0_gemm<<<NROW / 64, 256, 0, stream>>>(x, wtp, bih0, xpT);
    gru_fused<<<BSZ, 768, 0, stream>>>(xpT, whh0, bhh0, wih1, bih1, whh1, bhh1, hbuf);
    sindy_fused<<<NROW / 64, 512, 0, stream>>>(hbuf, bfa, ln1g, ln1b, b1, b2,
                                               ln2g, ln2b, out);
}

// Round 11
// 672.387 us; speedup vs baseline: 1.1807x; 1.1807x over previous
//
#include <hip/hip_runtime.h>
#include <hip/hip_bf16.h>
#include <math.h>

#define H 64
#define DM 128
#define GDIM 192      // 3*H
#define BSZ 32
#define SEQ 500
#define NROW (BSZ*SEQ)  // 16000
#define LIBN 2145
#define FFD 128
#define NKC2 75       // padded grouped-K chunks of 32 (2400 slots, 300 groups)
#define NGRP 300
#define CPK2 153600   // NKC2*4*64*8 shorts per layer

typedef __attribute__((ext_vector_type(8))) short short8;   // bf16x8 MFMA operand
typedef __attribute__((ext_vector_type(4))) float f32x4;    // MFMA accumulator
typedef __attribute__((ext_vector_type(2))) float f32x2;    // packed-math pair
typedef __attribute__((ext_vector_type(4))) unsigned u32x4;

__device__ __forceinline__ float sigf(float x) {
    return 1.0f / (1.0f + __expf(-x));
}
__device__ __forceinline__ float tanhfast(float x) {
    x = fminf(fmaxf(x, -15.0f), 15.0f);
    float t = __expf(-2.0f * x);
    return (1.0f - t) / (1.0f + t);
}
__device__ __forceinline__ short bf16r(float f) {   // fp32 -> bf16 rne
    unsigned u = __float_as_uint(f);
    unsigned r = (u + 0x7fffu + ((u >> 16) & 1u)) >> 16;
    return (short)r;
}
// packed dual-FMA: d.lo = a.lo*b.lo + c.lo, d.hi = a.hi*b.hi + c.hi (1 inst vs 2)
__device__ __forceinline__ f32x2 pkfma(f32x2 a, f32x2 b, f32x2 c) {
    f32x2 d;
    asm("v_pk_fma_f32 %0, %1, %2, %3" : "=v"(d) : "v"(a), "v"(b), "v"(c));
    return d;
}

// decode grouped-K group id -> (a, b): af[j] = z[a] * z[b + j], j = 0..7
__device__ __forceinline__ void grp_decode(int g, int& a, int& b) {
    if (g < 8) { a = 64; b = g * 8; }                 // linear: 1 * z[8g..8g+7]
    else if (g == 8 || g >= 297) { a = 64; b = 64; }  // const slot / padding
    else {
        int G = g - 9, acc = 0;
        a = 0; b = 0;
        for (int i2 = 0; i2 < 64; i2++) {
            int cnt = 8 - (i2 >> 3);                  // aligned 8-groups covering [i2,63]
            if (G < acc + cnt) { a = i2; b = ((i2 >> 3) + (G - acc)) * 8; break; }
            acc += cnt;
        }
    }
}

// ---------------- ONE fused pack kernel (unchanged) ----------------------------------
__global__ void pack_all(const float* __restrict__ wih0,
                         const float* __restrict__ coeffs,
                         const float* __restrict__ w1,
                         const float* __restrict__ w2,
                         float* __restrict__ wtp,
                         short* __restrict__ bfa) {
    int idx = blockIdx.x * 256 + threadIdx.x;        // grid covers exactly 364544
    if (idx < GDIM * DM) {                           // ---- wih0 -> wt2 (k-major) ----
        int k = idx / GDIM;
        int g = idx - k * GDIM;
        wtp[idx] = wih0[g * DM + k];
        return;
    }
    int r = idx - GDIM * DM;
    int l = r / (CPK2 + 2 * 8192);
    int q = r % (CPK2 + 2 * 8192);
    if (q < CPK2) {                                  // ---- coef (grouped-K) ----
        const float* coef = coeffs + (size_t)l * LIBN * H;
        int j = q & 7, lane = (q >> 3) & 63, nt = (q >> 9) & 3, kc = q >> 11;
        int grp = kc * 4 + (lane >> 4);
        int row = -1;
        if (grp < 8) row = 1 + grp * 8 + j;
        else if (grp == 8) row = (j == 0) ? 0 : -1;
        else if (grp < 297) {
            int a, b;
            grp_decode(grp, a, b);
            int jdx = b + j;
            if (jdx >= a) row = 65 + a * 64 - (a * (a - 1)) / 2 + (jdx - a);
        }
        int c = nt * 16 + (lane & 15);
        bfa[(size_t)l * CPK2 + q] = (row >= 0) ? bf16r(coef[(size_t)row * H + c]) : (short)0;
        return;
    }
    int q2 = q - CPK2;
    if (q2 < 8192) {                                 // ---- W1^T fragments ----
        const float* w1l = w1 + (size_t)l * FFD * H;
        int j = q2 & 7, lane = (q2 >> 3) & 63, nt = (q2 >> 9) & 7, kc = q2 >> 12;
        int k = kc * 32 + ((lane >> 4) << 3) + j;
        int n = nt * 16 + (lane & 15);
        bfa[(size_t)2 * CPK2 + l * 8192 + q2] = bf16r(w1l[(size_t)n * H + k]);
        return;
    }
    int q3 = q2 - 8192;                              // ---- W2^T fragments ----
    const float* w2l = w2 + (size_t)l * H * FFD;
    int j = q3 & 7, lane = (q3 >> 3) & 63, nt = (q3 >> 9) & 3, kc = q3 >> 11;
    int k = kc * 32 + ((lane >> 4) << 3) + j;
    int n = nt * 16 + (lane & 15);
    bfa[(size_t)2 * CPK2 + 2 * 8192 + l * 8192 + q3] = bf16r(w2l[(size_t)n * FFD + k]);
}

// ---------------- xp0 = x @ Wih0^T + bih0: register-tiled (R9, FROZEN) ---------------
__global__ __launch_bounds__(256, 1) void xp0_gemm(const float* __restrict__ x,
                                                   const float* __restrict__ wt2,
                                                   const float* __restrict__ bih0,
                                                   float* __restrict__ xpT) {
    __shared__ __align__(16) float wlds[DM * GDIM];   // 128 x 192 k-major, 96 KB
    int tid = threadIdx.x;
    int wv = __builtin_amdgcn_readfirstlane(tid >> 6);
    int lane = tid & 63;

    for (int p = tid; p < DM * GDIM / 4; p += 256)    // stage W^T: coalesced, one-time
        ((f32x4*)wlds)[p] = ((const f32x4*)wt2)[p];

    int i = lane >> 2;                                // row group 0..15
    int j = lane & 3;                                 // col group 0..3
    int rb = blockIdx.x * 64;
    int row0 = rb + 4 * i;

    f32x4 acc[3][4];
#pragma unroll
    for (int t = 0; t < 3; t++) {
        f32x4 bv = *(const f32x4*)(bih0 + 16 * (wv + 4 * t) + 4 * j);
#pragma unroll
        for (int ii = 0; ii < 4; ii++) acc[t][ii] = bv;
    }
    __syncthreads();

    const float* xr0 = x + (size_t)row0 * DM;
    for (int k4 = 0; k4 < 32; k4++) {
        f32x4 xr[4];
#pragma unroll
        for (int ii = 0; ii < 4; ii++)
            xr[ii] = *(const f32x4*)(xr0 + ii * DM + k4 * 4);
#pragma unroll
        for (int t = 0; t < 3; t++) {
            int cb = 16 * (wv + 4 * t);
#pragma unroll
            for (int e = 0; e < 4; e++) {
                f32x4 wvv = *(const f32x4*)&wlds[(k4 * 4 + e) * GDIM + cb + 4 * j];
#pragma unroll
                for (int ii = 0; ii < 4; ii++)
                    acc[t][ii] += wvv * xr[ii][e];
            }
        }
    }
    int bb = row0 / 500;
    int ss = row0 - bb * 500;
    float* base = xpT + ((size_t)(bb * 125 + (ss >> 2)) * GDIM) * 4;
#pragma unroll
    for (int t = 0; t < 3; t++) {
        int cb = 16 * (wv + 4 * t);
#pragma unroll
        for (int jj = 0; jj < 4; jj++) {
            int g = cb + 4 * j + jj;
            f32x4 v = { acc[t][0][jj], acc[t][1][jj], acc[t][2][jj], acc[t][3][jj] };
            *(f32x4*)(base + (size_t)g * 4) = v;
        }
    }
}

// ---------------- fused 2-layer GRU scan: R7 engine, 2 sequences per block -----------
// R10's single-barrier redundant-gate scheme failed (1.5M bank conflicts + scattered
// stores). This keeps the PROVEN R7 structure verbatim but: (a) K-split 2 instead of
// 4 (6 waves/seq, 32-wide K-chunks, 96 weight VGPRs); (b) TWO independent sequences
// per block (12 waves, 16 blocks). Both sequences share the two barriers, but their
// serial gate tails run on different waves concurrently -> the tail + rendezvous cost
// is amortized over 2 timesteps of work per step.
// Wave wv: sq = wv/6 (sequence), wl = wv%6, m = wl>>1 (matvec), q = wl&1 (K-half).
// Gate waves: wl==0 -> layer0, wl==4 (m=2,q=0) -> layer1 (one step skewed, as R7).
__global__ __launch_bounds__(768, 3) void gru_fused(const float* __restrict__ xpT,
                                                    const float* __restrict__ whh0,
                                                    const float* __restrict__ bhh0,
                                                    const float* __restrict__ wih1,
                                                    const float* __restrict__ bih1,
                                                    const float* __restrict__ whh1,
                                                    const float* __restrict__ bhh1,
                                                    float* __restrict__ hbuf) {
    int tid = threadIdx.x;
    int wv = __builtin_amdgcn_readfirstlane(tid >> 6);   // 0..11
    int lane = tid & 63;
    int sq = wv / 6;            // sequence slot within block
    int wl = wv % 6;
    int m = wl >> 1;            // 0: Whh0@h0, 1: Wih1@h0, 2: Whh1@h1
    int q = wl & 1;             // K-half
    int k0 = q * 32;
    int b = blockIdx.x * 2 + sq;

    __shared__ __align__(16) float h0s[2][H];
    __shared__ __align__(16) float h1s[2][H];
    __shared__ float part[2][3][2][GDIM];   // [seq][m][q][gate*64+row]

    if (tid < 2 * H) { ((float*)h0s)[tid] = 0.0f; ((float*)h1s)[tid] = 0.0f; }

    const float* W = (m == 0) ? whh0 : (m == 1) ? wih1 : whh1;
    f32x2 wrp[16], wzp[16], wnp[16];       // 96 weight VGPRs (K=32 per wave)
#pragma unroll
    for (int k4 = 0; k4 < 8; k4++) {
        f32x4 a = ((const f32x4*)(W + (size_t)lane * H + k0))[k4];
        f32x4 c = ((const f32x4*)(W + (size_t)(H + lane) * H + k0))[k4];
        f32x4 d = ((const f32x4*)(W + (size_t)(2 * H + lane) * H + k0))[k4];
        wrp[2*k4]   = __builtin_shufflevector(a, a, 0, 1);
        wrp[2*k4+1] = __builtin_shufflevector(a, a, 2, 3);
        wzp[2*k4]   = __builtin_shufflevector(c, c, 0, 1);
        wzp[2*k4+1] = __builtin_shufflevector(c, c, 2, 3);
        wnp[2*k4]   = __builtin_shufflevector(d, d, 0, 1);
        wnp[2*k4+1] = __builtin_shufflevector(d, d, 2, 3);
    }

    float b0r = 0, b0z = 0, b0n = 0;
    float b1ir = 0, b1iz = 0, b1in = 0, b1hr = 0, b1hz = 0, b1hn = 0;
    float hreg0 = 0.0f, hreg1 = 0.0f;
    float hb4[4] = {0.f, 0.f, 0.f, 0.f};
    f32x4 xc[4][3];
    const float* xpB = xpT + (size_t)b * 125 * GDIM * 4;

    if (wl == 0) {
        b0r = bhh0[lane]; b0z = bhh0[H + lane]; b0n = bhh0[2 * H + lane];
#pragma unroll
        for (int g3 = 0; g3 < 3; g3++) {
            xc[0][g3] = *(const f32x4*)(xpB + ((size_t)0 * GDIM + g3 * 64 + lane) * 4);
            xc[1][g3] = *(const f32x4*)(xpB + ((size_t)1 * GDIM + g3 * 64 + lane) * 4);
        }
    } else if (wl == 4) {
        b1ir = bih1[lane]; b1iz = bih1[H + lane]; b1in = bih1[2 * H + lane];
        b1hr = bhh1[lane]; b1hz = bhh1[H + lane]; b1hn = bhh1[2 * H + lane];
    }
    __syncthreads();

    auto loadch = [&](int c, int buf) {
        if (c < 125) {
#pragma unroll
            for (int g3 = 0; g3 < 3; g3++)
                xc[buf][g3] = *(const f32x4*)(xpB + ((size_t)c * GDIM + g3 * 64 + lane) * 4);
        }
    };

    auto step = [&](int s, int e, float xr, float xz, float xn) {
        // phase 1: partial matvec over K-half [k0, k0+32); uniform-addr LDS broadcast
        const float* hv = (m == 2) ? h1s[sq] : h0s[sq];
        f32x2 arp = {0.f, 0.f}, azp = {0.f, 0.f}, anp = {0.f, 0.f};
#pragma unroll
        for (int t4 = 0; t4 < 8; t4++) {
            f32x4 h4 = ((const f32x4*)(hv + k0))[t4];
            f32x2 hlo = __builtin_shufflevector(h4, h4, 0, 1);
            f32x2 hhi = __builtin_shufflevector(h4, h4, 2, 3);
            arp = pkfma(wrp[2*t4], hlo, arp);
            arp = pkfma(wrp[2*t4+1], hhi, arp);
            azp = pkfma(wzp[2*t4], hlo, azp);
            azp = pkfma(wzp[2*t4+1], hhi, azp);
            anp = pkfma(wnp[2*t4], hlo, anp);
            anp = pkfma(wnp[2*t4+1], hhi, anp);
        }
        part[sq][m][q][lane]         = arp[0] + arp[1];
        part[sq][m][q][H + lane]     = azp[0] + azp[1];
        part[sq][m][q][2 * H + lane] = anp[0] + anp[1];
        __syncthreads();

        // phase 2: gate waves (one per layer per sequence; tails overlap across seqs)
        if (wl == 0) {
            if (s < SEQ) {
                float gr = b0r + part[sq][0][0][lane] + part[sq][0][1][lane];
                float gz = b0z + part[sq][0][0][H + lane] + part[sq][0][1][H + lane];
                float gn = b0n + part[sq][0][0][2*H + lane] + part[sq][0][1][2*H + lane];
                float rg = sigf(xr + gr);
                float zg = sigf(xz + gz);
                float ng = tanhfast(xn + rg * gn);
                hreg0 = (1.0f - zg) * ng + zg * hreg0;
                h0s[sq][lane] = hreg0;
            }
        } else if (wl == 4) {
            if (s >= 1) {
                float xr1 = b1ir + part[sq][1][0][lane] + part[sq][1][1][lane];
                float xz1 = b1iz + part[sq][1][0][H + lane] + part[sq][1][1][H + lane];
                float xn1 = b1in + part[sq][1][0][2*H + lane] + part[sq][1][1][2*H + lane];
                float gr1 = b1hr + part[sq][2][0][lane] + part[sq][2][1][lane];
                float gz1 = b1hz + part[sq][2][0][H + lane] + part[sq][2][1][H + lane];
                float gn1 = b1hn + part[sq][2][0][2*H + lane] + part[sq][2][1][2*H + lane];
                float rg = sigf(xr1 + gr1);
                float zg = sigf(xz1 + gz1);
                float ng = tanhfast(xn1 + rg * gn1);
                hreg1 = (1.0f - zg) * ng + zg * hreg1;
                h1s[sq][lane] = hreg1;
                hb4[(e + 3) & 3] = hreg1;                 // h1[s-1], (s-1)&3 == (e+3)&3
                if (e == 0) {                              // s in {4,8,...,500}: flush h1[s-4..s-1]
                    float* dst = hbuf + ((size_t)b * SEQ + (s - 4)) * H + lane;
#pragma unroll
                    for (int t = 0; t < 4; t++) dst[t * H] = hb4[t];
                }
            }
        }
        __syncthreads();
    };

    for (int scb = 0; scb < 31; scb++) {
#pragma unroll
        for (int sci = 0; sci < 4; sci++) {
            int sc = scb * 4 + sci;
            if (wl == 0 && (sci & 1) == 0) {
                loadch(sc + 2, (sci + 2) & 3);
                loadch(sc + 3, (sci + 3) & 3);
            }
            int s0 = sc * 4;
            step(s0 + 0, 0, xc[sci][0][0], xc[sci][1][0], xc[sci][2][0]);
            step(s0 + 1, 1, xc[sci][0][1], xc[sci][1][1], xc[sci][2][1]);
            step(s0 + 2, 2, xc[sci][0][2], xc[sci][1][2], xc[sci][2][2]);
            step(s0 + 3, 3, xc[sci][0][3], xc[sci][1][3], xc[sci][2][3]);
        }
    }
    {   // sc = 124 (buf 0, loaded at sc=122)
        step(496, 0, xc[0][0][0], xc[0][1][0], xc[0][2][0]);
        step(497, 1, xc[0][0][1], xc[0][1][1], xc[0][2][1]);
        step(498, 2, xc[0][0][2], xc[0][1][2], xc[0][2][2]);
        step(499, 3, xc[0][0][3], xc[0][1][3], xc[0][2][3]);
    }
    // tail s = 500: produces h1[499] and flushes h1[496..499]
    step(500, 0, 0.0f, 0.0f, 0.0f);
}

// ---------------- FUSED 2-layer SINDy kernel + parallel LN (R8, FROZEN) --------------
__global__ __launch_bounds__(512) void sindy_fused(const float* __restrict__ hbuf_in,
                                                   const short* __restrict__ bfa,
                                                   const float* __restrict__ ln1g,
                                                   const float* __restrict__ ln1b,
                                                   const float* __restrict__ b1g,
                                                   const float* __restrict__ b2g,
                                                   const float* __restrict__ ln2g,
                                                   const float* __restrict__ ln2b,
                                                   float* __restrict__ out) {
    __shared__ float z[65 * 68];                   // row 64 = zero pad (safe b-reads)
    __shared__ float upd[64 * 68];
    __shared__ float ff[64 * 132];
    __shared__ unsigned kmap2[NGRP];
    __shared__ float bfs1[2][FFD], bfs2[2][H];
    __shared__ float g1s[2][H], b1s[2][H], g2s[2][H], b2s[2][H];

    int tid = threadIdx.x;
    int wv = __builtin_amdgcn_readfirstlane(tid >> 6);
    int lane = tid & 63;
    int row0 = blockIdx.x * 64;

    for (int idx = tid; idx < 64 * 16; idx += 512) {
        int r = idx >> 4, c4 = idx & 15;
        *(f32x4*)&z[r * 68 + c4 * 4] = *(const f32x4*)&hbuf_in[(size_t)(row0 + r) * H + c4 * 4];
    }
    for (int idx = tid; idx < 64 * 17; idx += 512)
        *(f32x4*)&upd[idx * 4] = (f32x4){0.f, 0.f, 0.f, 0.f};
    if (tid < 64) {
        z[tid * 68 + 64] = 1.0f; z[tid * 68 + 65] = 0.0f;
        z[tid * 68 + 66] = 0.0f; z[tid * 68 + 67] = 0.0f;
    }
    if (tid < 68) z[64 * 68 + tid] = 0.0f;         // zero pad row
    if (tid < NGRP) {
        int a, b;
        grp_decode(tid, a, b);
        kmap2[tid] = ((unsigned)a << 16) | (unsigned)b;
    }
    if (tid < FFD) { bfs1[0][tid] = b1g[tid]; bfs1[1][tid] = b1g[FFD + tid]; }
    if (tid < H) {
        bfs2[0][tid] = b2g[tid];      bfs2[1][tid] = b2g[H + tid];
        g1s[0][tid] = ln1g[tid];      g1s[1][tid] = ln1g[H + tid];
        b1s[0][tid] = ln1b[tid];      b1s[1][tid] = ln1b[H + tid];
        g2s[0][tid] = ln2g[tid];      g2s[1][tid] = ln2g[H + tid];
        b2s[0][tid] = ln2b[tid];      b2s[1][tid] = ln2b[H + tid];
    }
    __syncthreads();

    int kj0 = ((lane >> 4) << 3);
    int m0 = (wv & 3) * 16;
    int m = m0 + (lane & 15);
    int rbase = m0 + ((lane >> 4) << 2);
    int cb16 = lane & 15;
    const float* zrow = &z[m * 68];
    int lrow = tid >> 3;                           // parallel-LN: row, 8 threads/row
    int lk = (tid & 7) * 8;                        // this thread's 8-col slice

#pragma unroll
    for (int l = 0; l < 2; l++) {
        const short* cpk = bfa + (size_t)l * CPK2;
        const short* w1p = bfa + (size_t)2 * CPK2 + l * 8192;
        const short* w2p = bfa + (size_t)2 * CPK2 + 2 * 8192 + l * 8192;

        // ---- phase 1: upd = theta @ coef (grouped-K, k-split 2-way) ----
        {
            int p = wv >> 2;
            f32x4 acc[4] = {{0,0,0,0},{0,0,0,0},{0,0,0,0},{0,0,0,0}};
            for (int kc = p; kc < NKC2; kc += 2) {
                unsigned ab = kmap2[kc * 4 + (lane >> 4)];
                float za = zrow[ab >> 16];
                const float* zb = &zrow[ab & 0xffffu];
                f32x4 z0 = *(const f32x4*)zb;
                f32x4 z1 = *(const f32x4*)(zb + 4);
                short8 af;
                af[0] = bf16r(za * z0[0]);
                af[1] = bf16r(za * z0[1]);
                af[2] = bf16r(za * z0[2]);
                af[3] = bf16r(za * z0[3]);
                af[4] = bf16r(za * z1[0]);
                af[5] = bf16r(za * z1[1]);
                af[6] = bf16r(za * z1[2]);
                af[7] = bf16r(za * z1[3]);
                const short* cb = cpk + ((size_t)(kc * 4) * 64 + lane) * 8;
#pragma unroll
                for (int nt = 0; nt < 4; nt++) {
                    short8 bf = *(const short8*)(cb + (size_t)nt * 512);
                    acc[nt] = __builtin_amdgcn_mfma_f32_16x16x32_bf16(af, bf, acc[nt], 0, 0, 0);
                }
            }
#pragma unroll
            for (int nt = 0; nt < 4; nt++)
#pragma unroll
                for (int r = 0; r < 4; r++)
                    atomicAdd(&upd[(rbase + r) * 68 + nt * 16 + cb16], acc[nt][r]);
        }
        __syncthreads();

        // ---- LN1 (all 512 threads, 8/row) -> z ----
        {
            float v[8];
            float s1 = 0.0f;
#pragma unroll
            for (int i = 0; i < 8; i++) {
                v[i] = z[lrow * 68 + lk + i] + upd[lrow * 68 + lk + i];
                s1 += v[i];
            }
            s1 += __shfl_xor(s1, 1); s1 += __shfl_xor(s1, 2); s1 += __shfl_xor(s1, 4);
            float mn = s1 * (1.0f / 64.0f);
            float s2 = 0.0f;
#pragma unroll
            for (int i = 0; i < 8; i++) { float d = v[i] - mn; s2 += d * d; }
            s2 += __shfl_xor(s2, 1); s2 += __shfl_xor(s2, 2); s2 += __shfl_xor(s2, 4);
            float rstd = 1.0f / sqrtf(s2 * (1.0f / 64.0f) + 1e-5f);
#pragma unroll
            for (int i = 0; i < 8; i++)
                z[lrow * 68 + lk + i] = (v[i] - mn) * rstd * g1s[l][lk + i] + b1s[l][lk + i];
        }
        __syncthreads();

        // ---- phase 3: ff = gelu(LN1 @ W1^T + b1) ----
        {
            int nq = wv >> 2;
            f32x4 acc[4] = {{0,0,0,0},{0,0,0,0},{0,0,0,0},{0,0,0,0}};
#pragma unroll
            for (int kc = 0; kc < 2; kc++) {
                f32x4 za = *(const f32x4*)&z[m * 68 + kc * 32 + kj0];
                f32x4 zb = *(const f32x4*)&z[m * 68 + kc * 32 + kj0 + 4];
                short8 af;
                af[0] = bf16r(za[0]); af[1] = bf16r(za[1]); af[2] = bf16r(za[2]); af[3] = bf16r(za[3]);
                af[4] = bf16r(zb[0]); af[5] = bf16r(zb[1]); af[6] = bf16r(zb[2]); af[7] = bf16r(zb[3]);
#pragma unroll
                for (int t = 0; t < 4; t++) {
                    int nt = nq * 4 + t;
                    short8 bf = *(const short8*)(w1p + ((size_t)(kc * 8 + nt) * 64 + lane) * 8);
                    acc[t] = __builtin_amdgcn_mfma_f32_16x16x32_bf16(af, bf, acc[t], 0, 0, 0);
                }
            }
#pragma unroll
            for (int t = 0; t < 4; t++) {
                int col = (nq * 4 + t) * 16 + cb16;
#pragma unroll
                for (int r = 0; r < 4; r++) {
                    float v = acc[t][r] + bfs1[l][col];
                    ff[(rbase + r) * 132 + col] = 0.5f * v * (1.0f + erff(v * 0.70710678118654752f));
                }
            }
        }
        __syncthreads();

        // ---- phase 5: upd = ff @ W2^T + b2 (plain stores, full overwrite) ----
        {
            int nh = wv >> 2;
            f32x4 acc[2] = {{0,0,0,0},{0,0,0,0}};
            const float* frow = &ff[m * 132];
#pragma unroll
            for (int kc = 0; kc < 4; kc++) {
                f32x4 fa = *(const f32x4*)&frow[kc * 32 + kj0];
                f32x4 fb = *(const f32x4*)&frow[kc * 32 + kj0 + 4];
                short8 af;
                af[0] = bf16r(fa[0]); af[1] = bf16r(fa[1]); af[2] = bf16r(fa[2]); af[3] = bf16r(fa[3]);
                af[4] = bf16r(fb[0]); af[5] = bf16r(fb[1]); af[6] = bf16r(fb[2]); af[7] = bf16r(fb[3]);
#pragma unroll
                for (int t = 0; t < 2; t++) {
                    int nt = nh * 2 + t;
                    short8 bf = *(const short8*)(w2p + ((size_t)(kc * 4 + nt) * 64 + lane) * 8);
                    acc[t] = __builtin_amdgcn_mfma_f32_16x16x32_bf16(af, bf, acc[t], 0, 0, 0);
                }
            }
#pragma unroll
            for (int t = 0; t < 2; t++) {
                int col = (nh * 2 + t) * 16 + cb16;
#pragma unroll
                for (int r = 0; r < 4; r++)
                    upd[(rbase + r) * 68 + col] = acc[t][r] + bfs2[l][col];
            }
        }
        __syncthreads();

        // ---- LN2 (all 512 threads): l=0 -> z (stay in LDS); l=1 -> out ----
        {
            float v[8];
            float s1 = 0.0f;
#pragma unroll
            for (int i = 0; i < 8; i++) {
                v[i] = z[lrow * 68 + lk + i] + upd[lrow * 68 + lk + i];
                s1 += v[i];
            }
            s1 += __shfl_xor(s1, 1); s1 += __shfl_xor(s1, 2); s1 += __shfl_xor(s1, 4);
            float mn = s1 * (1.0f / 64.0f);
            float s2 = 0.0f;
#pragma unroll
            for (int i = 0; i < 8; i++) { float d = v[i] - mn; s2 += d * d; }
            s2 += __shfl_xor(s2, 1); s2 += __shfl_xor(s2, 2); s2 += __shfl_xor(s2, 4);
            float rstd = 1.0f / sqrtf(s2 * (1.0f / 64.0f) + 1e-5f);
            if (l == 0) {
#pragma unroll
                for (int i = 0; i < 8; i++)
                    z[lrow * 68 + lk + i] = (v[i] - mn) * rstd * g2s[0][lk + i] + b2s[0][lk + i];
            } else {
                int row = row0 + lrow;
                int last = (row % SEQ == SEQ - 1);
#pragma unroll
                for (int i = 0; i < 8; i++) {
                    float res = (v[i] - mn) * rstd * g2s[1][lk + i] + b2s[1][lk + i];
                    out[(size_t)row * H + lk + i] = res;
                    if (last)
                        out[(size_t)NROW * H + (row / SEQ) * H + lk + i] = res;
                }
            }
        }
        __syncthreads();

        if (l == 0) {   // re-zero upd for layer 1's atomicAdd accumulation
            for (int idx = tid; idx < 64 * 17; idx += 512)
                *(f32x4*)&upd[idx * 4] = (f32x4){0.f, 0.f, 0.f, 0.f};
            __syncthreads();
        }
    }
}

extern "C" void kernel_launch(void* const* d_in, const int* in_sizes, int n_in,
                              void* d_out, int out_size, void* d_ws, size_t ws_size,
                              hipStream_t stream) {
    const float* x    = (const float*)d_in[0];
    const float* wih0 = (const float*)d_in[1];
    const float* whh0 = (const float*)d_in[2];
    const float* bih0 = (const float*)d_in[3];
    const float* bhh0 = (const float*)d_in[4];
    const float* wih1 = (const float*)d_in[5];
    const float* whh1 = (const float*)d_in[6];
    const float* bih1 = (const float*)d_in[7];
    const float* bhh1 = (const float*)d_in[8];
    const float* coeffs = (const float*)d_in[9];
    const float* ln1g = (const float*)d_in[10];
    const float* ln1b = (const float*)d_in[11];
    const float* w1   = (const float*)d_in[12];
    const float* b1   = (const float*)d_in[13];
    const float* w2   = (const float*)d_in[14];
    const float* b2   = (const float*)d_in[15];
    const float* ln2g = (const float*)d_in[16];
    const float* ln2b = (const float*)d_in[17];

    float* out = (float*)d_out;
    float* ws  = (float*)d_ws;
    float* xpT = ws;                               // 16000*192 = 3,072,000 floats
    float* wtp = ws + (size_t)NROW * GDIM;         // 24,576 floats (k-major W^T)
    short* bfa = (short*)(wtp + GDIM * DM);        // bf16 fragment area
    float* hbuf = out;                             // reuse first 1,024,000 floats of d_out

    // one fused pack launch: 24576 + 2*(153600+8192+8192) = 364544 = 1424*256
    pack_all<<<1424, 256, 0, stream>>>(wih0, coeffs, w1, w2, wtp, bfa);
    xp0_gemm<<<NROW / 64, 256, 0, stream>>>(x, wtp, bih0, xpT);
    gru_fused<<<BSZ / 2, 768, 0, stream>>>(xpT, whh0, bhh0, wih1, bih1, whh1, bhh1, hbuf);
    sindy_fused<<<NROW / 64, 512, 0, stream>>>(hbuf, bfa, ln1g, ln1b, b1, b2,
                                               ln2g, ln2b, out);
}

// Round 12
// 466.549 us; speedup vs baseline: 1.7016x; 1.4412x over previous
//
#include <hip/hip_runtime.h>
#include <hip/hip_bf16.h>
#include <math.h>

#define H 64
#define DM 128
#define GDIM 192      // 3*H
#define BSZ 32
#define SEQ 500
#define NROW (BSZ*SEQ)  // 16000
#define LIBN 2145
#define FFD 128
#define NKC2 75       // padded grouped-K chunks of 32 (2400 slots, 300 groups)
#define NGRP 300
#define CPK2 153600   // NKC2*4*64*8 shorts per layer

typedef __attribute__((ext_vector_type(8))) short short8;   // bf16x8 MFMA operand
typedef __attribute__((ext_vector_type(4))) float f32x4;    // MFMA accumulator
typedef __attribute__((ext_vector_type(2))) float f32x2;    // packed-math pair
typedef __attribute__((ext_vector_type(4))) unsigned u32x4;

__device__ __forceinline__ float sigf(float x) {
    return 1.0f / (1.0f + __expf(-x));
}
__device__ __forceinline__ float tanhfast(float x) {
    x = fminf(fmaxf(x, -15.0f), 15.0f);
    float t = __expf(-2.0f * x);
    return (1.0f - t) / (1.0f + t);
}
__device__ __forceinline__ short bf16r(float f) {   // fp32 -> bf16 rne
    unsigned u = __float_as_uint(f);
    unsigned r = (u + 0x7fffu + ((u >> 16) & 1u)) >> 16;
    return (short)r;
}
// packed dual-FMA: d.lo = a.lo*b.lo + c.lo, d.hi = a.hi*b.hi + c.hi (1 inst vs 2)
__device__ __forceinline__ f32x2 pkfma(f32x2 a, f32x2 b, f32x2 c) {
    f32x2 d;
    asm("v_pk_fma_f32 %0, %1, %2, %3" : "=v"(d) : "v"(a), "v"(b), "v"(c));
    return d;
}

// decode grouped-K group id -> (a, b): af[j] = z[a] * z[b + j], j = 0..7
__device__ __forceinline__ void grp_decode(int g, int& a, int& b) {
    if (g < 8) { a = 64; b = g * 8; }                 // linear: 1 * z[8g..8g+7]
    else if (g == 8 || g >= 297) { a = 64; b = 64; }  // const slot / padding
    else {
        int G = g - 9, acc = 0;
        a = 0; b = 0;
        for (int i2 = 0; i2 < 64; i2++) {
            int cnt = 8 - (i2 >> 3);                  // aligned 8-groups covering [i2,63]
            if (G < acc + cnt) { a = i2; b = ((i2 >> 3) + (G - acc)) * 8; break; }
            acc += cnt;
        }
    }
}

// ---------------- ONE fused pack kernel -----------------------------------------------
__global__ void pack_all(const float* __restrict__ wih0,
                         const float* __restrict__ coeffs,
                         const float* __restrict__ w1,
                         const float* __restrict__ w2,
                         float* __restrict__ wtp,
                         short* __restrict__ bfa) {
    int idx = blockIdx.x * 256 + threadIdx.x;        // grid covers exactly 364544
    if (idx < GDIM * DM) {                           // ---- wih0 -> wt2 (k-major) ----
        int k = idx / GDIM;
        int g = idx - k * GDIM;
        wtp[idx] = wih0[g * DM + k];
        return;
    }
    int r = idx - GDIM * DM;
    int l = r / (CPK2 + 2 * 8192);
    int q = r % (CPK2 + 2 * 8192);
    if (q < CPK2) {                                  // ---- coef (grouped-K) ----
        const float* coef = coeffs + (size_t)l * LIBN * H;
        int j = q & 7, lane = (q >> 3) & 63, nt = (q >> 9) & 3, kc = q >> 11;
        int grp = kc * 4 + (lane >> 4);
        int row = -1;
        if (grp < 8) row = 1 + grp * 8 + j;
        else if (grp == 8) row = (j == 0) ? 0 : -1;
        else if (grp < 297) {
            int a, b;
            grp_decode(grp, a, b);
            int jdx = b + j;
            if (jdx >= a) row = 65 + a * 64 - (a * (a - 1)) / 2 + (jdx - a);
        }
        int c = nt * 16 + (lane & 15);
        bfa[(size_t)l * CPK2 + q] = (row >= 0) ? bf16r(coef[(size_t)row * H + c]) : (short)0;
        return;
    }
    int q2 = q - CPK2;
    if (q2 < 8192) {                                 // ---- W1^T fragments ----
        const float* w1l = w1 + (size_t)l * FFD * H;
        int j = q2 & 7, lane = (q2 >> 3) & 63, nt = (q2 >> 9) & 7, kc = q2 >> 12;
        int k = kc * 32 + ((lane >> 4) << 3) + j;
        int n = nt * 16 + (lane & 15);
        bfa[(size_t)2 * CPK2 + l * 8192 + q2] = bf16r(w1l[(size_t)n * H + k]);
        return;
    }
    int q3 = q2 - 8192;                              // ---- W2^T fragments ----
    const float* w2l = w2 + (size_t)l * H * FFD;
    int j = q3 & 7, lane = (q3 >> 3) & 63, nt = (q3 >> 9) & 3, kc = q3 >> 11;
    int k = kc * 32 + ((lane >> 4) << 3) + j;
    int n = nt * 16 + (lane & 15);
    bfa[(size_t)2 * CPK2 + 2 * 8192 + l * 8192 + q3] = bf16r(w2l[(size_t)n * FFD + k]);
}

// ---------------- xp0 = x @ Wih0^T + bih0: register-tiled (R9, FROZEN) ---------------
__global__ __launch_bounds__(256, 1) void xp0_gemm(const float* __restrict__ x,
                                                   const float* __restrict__ wt2,
                                                   const float* __restrict__ bih0,
                                                   float* __restrict__ xpT) {
    __shared__ __align__(16) float wlds[DM * GDIM];   // 128 x 192 k-major, 96 KB
    int tid = threadIdx.x;
    int wv = __builtin_amdgcn_readfirstlane(tid >> 6);
    int lane = tid & 63;

    for (int p = tid; p < DM * GDIM / 4; p += 256)    // stage W^T: coalesced, one-time
        ((f32x4*)wlds)[p] = ((const f32x4*)wt2)[p];

    int i = lane >> 2;                                // row group 0..15
    int j = lane & 3;                                 // col group 0..3
    int rb = blockIdx.x * 64;
    int row0 = rb + 4 * i;

    f32x4 acc[3][4];
#pragma unroll
    for (int t = 0; t < 3; t++) {
        f32x4 bv = *(const f32x4*)(bih0 + 16 * (wv + 4 * t) + 4 * j);
#pragma unroll
        for (int ii = 0; ii < 4; ii++) acc[t][ii] = bv;
    }
    __syncthreads();

    const float* xr0 = x + (size_t)row0 * DM;
    for (int k4 = 0; k4 < 32; k4++) {
        f32x4 xr[4];
#pragma unroll
        for (int ii = 0; ii < 4; ii++)
            xr[ii] = *(const f32x4*)(xr0 + ii * DM + k4 * 4);
#pragma unroll
        for (int t = 0; t < 3; t++) {
            int cb = 16 * (wv + 4 * t);
#pragma unroll
            for (int e = 0; e < 4; e++) {
                f32x4 wvv = *(const f32x4*)&wlds[(k4 * 4 + e) * GDIM + cb + 4 * j];
#pragma unroll
                for (int ii = 0; ii < 4; ii++)
                    acc[t][ii] += wvv * xr[ii][e];
            }
        }
    }
    int bb = row0 / 500;
    int ss = row0 - bb * 500;
    float* base = xpT + ((size_t)(bb * 125 + (ss >> 2)) * GDIM) * 4;
#pragma unroll
    for (int t = 0; t < 3; t++) {
        int cb = 16 * (wv + 4 * t);
#pragma unroll
        for (int jj = 0; jj < 4; jj++) {
            int g = cb + 4 * j + jj;
            f32x4 v = { acc[t][0][jj], acc[t][1][jj], acc[t][2][jj], acc[t][3][jj] };
            *(f32x4*)(base + (size_t)g * 4) = v;
        }
    }
}

// ---------------- fused 2-layer GRU scan: R7 12-wave + pk_fma (275 µs, FROZEN) -------
__global__ __launch_bounds__(768, 3) void gru_fused(const float* __restrict__ xpT,
                                                    const float* __restrict__ whh0,
                                                    const float* __restrict__ bhh0,
                                                    const float* __restrict__ wih1,
                                                    const float* __restrict__ bih1,
                                                    const float* __restrict__ whh1,
                                                    const float* __restrict__ bhh1,
                                                    float* __restrict__ hbuf) {
    int b = blockIdx.x;
    int tid = threadIdx.x;
    int wv = __builtin_amdgcn_readfirstlane(tid >> 6);
    int lane = tid & 63;
    int m = wv % 3;
    int q = wv / 3;
    int k0 = q * 16;

    __shared__ __align__(16) float h0s[H];
    __shared__ __align__(16) float h1s[H];
    __shared__ float part[3][4][GDIM];

    if (tid < H) { h0s[tid] = 0.0f; h1s[tid] = 0.0f; }

    const float* W = (m == 0) ? whh0 : (m == 1) ? wih1 : whh1;
    f32x2 wrp[8], wzp[8], wnp[8];                  // 48 weight VGPRs as f32x2 pairs
#pragma unroll
    for (int k4 = 0; k4 < 4; k4++) {
        f32x4 a = ((const f32x4*)(W + (size_t)lane * H + k0))[k4];
        f32x4 c = ((const f32x4*)(W + (size_t)(H + lane) * H + k0))[k4];
        f32x4 d = ((const f32x4*)(W + (size_t)(2 * H + lane) * H + k0))[k4];
        wrp[2*k4]   = __builtin_shufflevector(a, a, 0, 1);
        wrp[2*k4+1] = __builtin_shufflevector(a, a, 2, 3);
        wzp[2*k4]   = __builtin_shufflevector(c, c, 0, 1);
        wzp[2*k4+1] = __builtin_shufflevector(c, c, 2, 3);
        wnp[2*k4]   = __builtin_shufflevector(d, d, 0, 1);
        wnp[2*k4+1] = __builtin_shufflevector(d, d, 2, 3);
    }

    float b0r = 0, b0z = 0, b0n = 0;
    float b1ir = 0, b1iz = 0, b1in = 0, b1hr = 0, b1hz = 0, b1hn = 0;
    float hreg0 = 0.0f, hreg1 = 0.0f;
    float hb4[4] = {0.f, 0.f, 0.f, 0.f};
    f32x4 xc[4][3];
    const float* xpB = xpT + (size_t)b * 125 * GDIM * 4;

    if (wv == 0) {
        b0r = bhh0[lane]; b0z = bhh0[H + lane]; b0n = bhh0[2 * H + lane];
#pragma unroll
        for (int g3 = 0; g3 < 3; g3++) {
            xc[0][g3] = *(const f32x4*)(xpB + ((size_t)0 * GDIM + g3 * 64 + lane) * 4);
            xc[1][g3] = *(const f32x4*)(xpB + ((size_t)1 * GDIM + g3 * 64 + lane) * 4);
        }
    } else if (wv == 2) {
        b1ir = bih1[lane]; b1iz = bih1[H + lane]; b1in = bih1[2 * H + lane];
        b1hr = bhh1[lane]; b1hz = bhh1[H + lane]; b1hn = bhh1[2 * H + lane];
    }
    __syncthreads();

    auto loadch = [&](int c, int buf) {
        if (c < 125) {
#pragma unroll
            for (int g3 = 0; g3 < 3; g3++)
                xc[buf][g3] = *(const f32x4*)(xpB + ((size_t)c * GDIM + g3 * 64 + lane) * 4);
        }
    };

    auto step = [&](int s, int e, float xr, float xz, float xn) {
        const float* hv = (m == 2) ? h1s : h0s;
        f32x2 arp = {0.f, 0.f}, azp = {0.f, 0.f}, anp = {0.f, 0.f};
#pragma unroll
        for (int t4 = 0; t4 < 4; t4++) {
            f32x4 h4 = ((const f32x4*)(hv + k0))[t4];
            f32x2 hlo = __builtin_shufflevector(h4, h4, 0, 1);
            f32x2 hhi = __builtin_shufflevector(h4, h4, 2, 3);
            arp = pkfma(wrp[2*t4], hlo, arp);
            arp = pkfma(wrp[2*t4+1], hhi, arp);
            azp = pkfma(wzp[2*t4], hlo, azp);
            azp = pkfma(wzp[2*t4+1], hhi, azp);
            anp = pkfma(wnp[2*t4], hlo, anp);
            anp = pkfma(wnp[2*t4+1], hhi, anp);
        }
        part[m][q][lane] = arp[0] + arp[1];
        part[m][q][H + lane] = azp[0] + azp[1];
        part[m][q][2 * H + lane] = anp[0] + anp[1];
        __syncthreads();

        if (wv == 0) {
            if (s < SEQ) {
                float gr = b0r, gz = b0z, gn = b0n;
#pragma unroll
                for (int qq = 0; qq < 4; qq++) {
                    gr += part[0][qq][lane];
                    gz += part[0][qq][H + lane];
                    gn += part[0][qq][2 * H + lane];
                }
                float rg = sigf(xr + gr);
                float zg = sigf(xz + gz);
                float ng = tanhfast(xn + rg * gn);
                hreg0 = (1.0f - zg) * ng + zg * hreg0;
                h0s[lane] = hreg0;
            }
        } else if (wv == 2) {
            if (s >= 1) {
                float xr1 = b1ir, xz1 = b1iz, xn1 = b1in;
                float gr1 = b1hr, gz1 = b1hz, gn1 = b1hn;
#pragma unroll
                for (int qq = 0; qq < 4; qq++) {
                    xr1 += part[1][qq][lane];
                    xz1 += part[1][qq][H + lane];
                    xn1 += part[1][qq][2 * H + lane];
                    gr1 += part[2][qq][lane];
                    gz1 += part[2][qq][H + lane];
                    gn1 += part[2][qq][2 * H + lane];
                }
                float rg = sigf(xr1 + gr1);
                float zg = sigf(xz1 + gz1);
                float ng = tanhfast(xn1 + rg * gn1);
                hreg1 = (1.0f - zg) * ng + zg * hreg1;
                h1s[lane] = hreg1;
                hb4[(e + 3) & 3] = hreg1;                 // h1[s-1], (s-1)&3 == (e+3)&3
                if (e == 0) {                              // s in {4,8,...,500}: flush h1[s-4..s-1]
                    float* dst = hbuf + ((size_t)b * SEQ + (s - 4)) * H + lane;
#pragma unroll
                    for (int t = 0; t < 4; t++) dst[t * H] = hb4[t];
                }
            }
        }
        __syncthreads();
    };

    for (int scb = 0; scb < 31; scb++) {
#pragma unroll
        for (int sci = 0; sci < 4; sci++) {
            int sc = scb * 4 + sci;
            if (wv == 0 && (sci & 1) == 0) {
                loadch(sc + 2, (sci + 2) & 3);
                loadch(sc + 3, (sci + 3) & 3);
            }
            int s0 = sc * 4;
            step(s0 + 0, 0, xc[sci][0][0], xc[sci][1][0], xc[sci][2][0]);
            step(s0 + 1, 1, xc[sci][0][1], xc[sci][1][1], xc[sci][2][1]);
            step(s0 + 2, 2, xc[sci][0][2], xc[sci][1][2], xc[sci][2][2]);
            step(s0 + 3, 3, xc[sci][0][3], xc[sci][1][3], xc[sci][2][3]);
        }
    }
    {   // sc = 124 (buf 0, loaded at sc=122)
        step(496, 0, xc[0][0][0], xc[0][1][0], xc[0][2][0]);
        step(497, 1, xc[0][0][1], xc[0][1][1], xc[0][2][1]);
        step(498, 2, xc[0][0][2], xc[0][1][2], xc[0][2][2]);
        step(499, 3, xc[0][0][3], xc[0][1][3], xc[0][2][3]);
    }
    // tail s = 500: produces h1[499] and flushes h1[496..499]
    step(500, 0, 0.0f, 0.0f, 0.0f);
}

// ---------------- FUSED 2-layer SINDy kernel + parallel LN (R8, FROZEN) --------------
__global__ __launch_bounds__(512) void sindy_fused(const float* __restrict__ hbuf_in,
                                                   const short* __restrict__ bfa,
                                                   const float* __restrict__ ln1g,
                                                   const float* __restrict__ ln1b,
                                                   const float* __restrict__ b1g,
                                                   const float* __restrict__ b2g,
                                                   const float* __restrict__ ln2g,
                                                   const float* __restrict__ ln2b,
                                                   float* __restrict__ out) {
    __shared__ float z[65 * 68];                   // row 64 = zero pad (safe b-reads)
    __shared__ float upd[64 * 68];
    __shared__ float ff[64 * 132];
    __shared__ unsigned kmap2[NGRP];
    __shared__ float bfs1[2][FFD], bfs2[2][H];
    __shared__ float g1s[2][H], b1s[2][H], g2s[2][H], b2s[2][H];

    int tid = threadIdx.x;
    int wv = __builtin_amdgcn_readfirstlane(tid >> 6);
    int lane = tid & 63;
    int row0 = blockIdx.x * 64;

    for (int idx = tid; idx < 64 * 16; idx += 512) {
        int r = idx >> 4, c4 = idx & 15;
        *(f32x4*)&z[r * 68 + c4 * 4] = *(const f32x4*)&hbuf_in[(size_t)(row0 + r) * H + c4 * 4];
    }
    for (int idx = tid; idx < 64 * 17; idx += 512)
        *(f32x4*)&upd[idx * 4] = (f32x4){0.f, 0.f, 0.f, 0.f};
    if (tid < 64) {
        z[tid * 68 + 64] = 1.0f; z[tid * 68 + 65] = 0.0f;
        z[tid * 68 + 66] = 0.0f; z[tid * 68 + 67] = 0.0f;
    }
    if (tid < 68) z[64 * 68 + tid] = 0.0f;         // zero pad row
    if (tid < NGRP) {
        int a, b;
        grp_decode(tid, a, b);
        kmap2[tid] = ((unsigned)a << 16) | (unsigned)b;
    }
    if (tid < FFD) { bfs1[0][tid] = b1g[tid]; bfs1[1][tid] = b1g[FFD + tid]; }
    if (tid < H) {
        bfs2[0][tid] = b2g[tid];      bfs2[1][tid] = b2g[H + tid];
        g1s[0][tid] = ln1g[tid];      g1s[1][tid] = ln1g[H + tid];
        b1s[0][tid] = ln1b[tid];      b1s[1][tid] = ln1b[H + tid];
        g2s[0][tid] = ln2g[tid];      g2s[1][tid] = ln2g[H + tid];
        b2s[0][tid] = ln2b[tid];      b2s[1][tid] = ln2b[H + tid];
    }
    __syncthreads();

    int kj0 = ((lane >> 4) << 3);
    int m0 = (wv & 3) * 16;
    int m = m0 + (lane & 15);
    int rbase = m0 + ((lane >> 4) << 2);
    int cb16 = lane & 15;
    const float* zrow = &z[m * 68];
    int lrow = tid >> 3;                           // parallel-LN: row, 8 threads/row
    int lk = (tid & 7) * 8;                        // this thread's 8-col slice

#pragma unroll
    for (int l = 0; l < 2; l++) {
        const short* cpk = bfa + (size_t)l * CPK2;
        const short* w1p = bfa + (size_t)2 * CPK2 + l * 8192;
        const short* w2p = bfa + (size_t)2 * CPK2 + 2 * 8192 + l * 8192;

        // ---- phase 1: upd = theta @ coef (grouped-K, k-split 2-way) ----
        {
            int p = wv >> 2;
            f32x4 acc[4] = {{0,0,0,0},{0,0,0,0},{0,0,0,0},{0,0,0,0}};
            for (int kc = p; kc < NKC2; kc += 2) {
                unsigned ab = kmap2[kc * 4 + (lane >> 4)];
                float za = zrow[ab >> 16];
                const float* zb = &zrow[ab & 0xffffu];
                f32x4 z0 = *(const f32x4*)zb;
                f32x4 z1 = *(const f32x4*)(zb + 4);
                short8 af;
                af[0] = bf16r(za * z0[0]);
                af[1] = bf16r(za * z0[1]);
                af[2] = bf16r(za * z0[2]);
                af[3] = bf16r(za * z0[3]);
                af[4] = bf16r(za * z1[0]);
                af[5] = bf16r(za * z1[1]);
                af[6] = bf16r(za * z1[2]);
                af[7] = bf16r(za * z1[3]);
                const short* cb = cpk + ((size_t)(kc * 4) * 64 + lane) * 8;
#pragma unroll
                for (int nt = 0; nt < 4; nt++) {
                    short8 bf = *(const short8*)(cb + (size_t)nt * 512);
                    acc[nt] = __builtin_amdgcn_mfma_f32_16x16x32_bf16(af, bf, acc[nt], 0, 0, 0);
                }
            }
#pragma unroll
            for (int nt = 0; nt < 4; nt++)
#pragma unroll
                for (int r = 0; r < 4; r++)
                    atomicAdd(&upd[(rbase + r) * 68 + nt * 16 + cb16], acc[nt][r]);
        }
        __syncthreads();

        // ---- LN1 (all 512 threads, 8/row) -> z ----
        {
            float v[8];
            float s1 = 0.0f;
#pragma unroll
            for (int i = 0; i < 8; i++) {
                v[i] = z[lrow * 68 + lk + i] + upd[lrow * 68 + lk + i];
                s1 += v[i];
            }
            s1 += __shfl_xor(s1, 1); s1 += __shfl_xor(s1, 2); s1 += __shfl_xor(s1, 4);
            float mn = s1 * (1.0f / 64.0f);
            float s2 = 0.0f;
#pragma unroll
            for (int i = 0; i < 8; i++) { float d = v[i] - mn; s2 += d * d; }
            s2 += __shfl_xor(s2, 1); s2 += __shfl_xor(s2, 2); s2 += __shfl_xor(s2, 4);
            float rstd = 1.0f / sqrtf(s2 * (1.0f / 64.0f) + 1e-5f);
#pragma unroll
            for (int i = 0; i < 8; i++)
                z[lrow * 68 + lk + i] = (v[i] - mn) * rstd * g1s[l][lk + i] + b1s[l][lk + i];
        }
        __syncthreads();

        // ---- phase 3: ff = gelu(LN1 @ W1^T + b1) ----
        {
            int nq = wv >> 2;
            f32x4 acc[4] = {{0,0,0,0},{0,0,0,0},{0,0,0,0},{0,0,0,0}};
#pragma unroll
            for (int kc = 0; kc < 2; kc++) {
                f32x4 za = *(const f32x4*)&z[m * 68 + kc * 32 + kj0];
                f32x4 zb = *(const f32x4*)&z[m * 68 + kc * 32 + kj0 + 4];
                short8 af;
                af[0] = bf16r(za[0]); af[1] = bf16r(za[1]); af[2] = bf16r(za[2]); af[3] = bf16r(za[3]);
                af[4] = bf16r(zb[0]); af[5] = bf16r(zb[1]); af[6] = bf16r(zb[2]); af[7] = bf16r(zb[3]);
#pragma unroll
                for (int t = 0; t < 4; t++) {
                    int nt = nq * 4 + t;
                    short8 bf = *(const short8*)(w1p + ((size_t)(kc * 8 + nt) * 64 + lane) * 8);
                    acc[t] = __builtin_amdgcn_mfma_f32_16x16x32_bf16(af, bf, acc[t], 0, 0, 0);
                }
            }
#pragma unroll
            for (int t = 0; t < 4; t++) {
                int col = (nq * 4 + t) * 16 + cb16;
#pragma unroll
                for (int r = 0; r < 4; r++) {
                    float v = acc[t][r] + bfs1[l][col];
                    ff[(rbase + r) * 132 + col] = 0.5f * v * (1.0f + erff(v * 0.70710678118654752f));
                }
            }
        }
        __syncthreads();

        // ---- phase 5: upd = ff @ W2^T + b2 (plain stores, full overwrite) ----
        {
            int nh = wv >> 2;
            f32x4 acc[2] = {{0,0,0,0},{0,0,0,0}};
            const float* frow = &ff[m * 132];
#pragma unroll
            for (int kc = 0; kc < 4; kc++) {
                f32x4 fa = *(const f32x4*)&frow[kc * 32 + kj0];
                f32x4 fb = *(const f32x4*)&frow[kc * 32 + kj0 + 4];
                short8 af;
                af[0] = bf16r(fa[0]); af[1] = bf16r(fa[1]); af[2] = bf16r(fa[2]); af[3] = bf16r(fa[3]);
                af[4] = bf16r(fb[0]); af[5] = bf16r(fb[1]); af[6] = bf16r(fb[2]); af[7] = bf16r(fb[3]);
#pragma unroll
                for (int t = 0; t < 2; t++) {
                    int nt = nh * 2 + t;
                    short8 bf = *(const short8*)(w2p + ((size_t)(kc * 4 + nt) * 64 + lane) * 8);
                    acc[t] = __builtin_amdgcn_mfma_f32_16x16x32_bf16(af, bf, acc[t], 0, 0, 0);
                }
            }
#pragma unroll
            for (int t = 0; t < 2; t++) {
                int col = (nh * 2 + t) * 16 + cb16;
#pragma unroll
                for (int r = 0; r < 4; r++)
                    upd[(rbase + r) * 68 + col] = acc[t][r] + bfs2[l][col];
            }
        }
        __syncthreads();

        // ---- LN2 (all 512 threads): l=0 -> z (stay in LDS); l=1 -> out ----
        {
            float v[8];
            float s1 = 0.0f;
#pragma unroll
            for (int i = 0; i < 8; i++) {
                v[i] = z[lrow * 68 + lk + i] + upd[lrow * 68 + lk + i];
                s1 += v[i];
            }
            s1 += __shfl_xor(s1, 1); s1 += __shfl_xor(s1, 2); s1 += __shfl_xor(s1, 4);
            float mn = s1 * (1.0f / 64.0f);
            float s2 = 0.0f;
#pragma unroll
            for (int i = 0; i < 8; i++) { float d = v[i] - mn; s2 += d * d; }
            s2 += __shfl_xor(s2, 1); s2 += __shfl_xor(s2, 2); s2 += __shfl_xor(s2, 4);
            float rstd = 1.0f / sqrtf(s2 * (1.0f / 64.0f) + 1e-5f);
            if (l == 0) {
#pragma unroll
                for (int i = 0; i < 8; i++)
                    z[lrow * 68 + lk + i] = (v[i] - mn) * rstd * g2s[0][lk + i] + b2s[0][lk + i];
            } else {
                int row = row0 + lrow;
                int last = (row % SEQ == SEQ - 1);
#pragma unroll
                for (int i = 0; i < 8; i++) {
                    float res = (v[i] - mn) * rstd * g2s[1][lk + i] + b2s[1][lk + i];
                    out[(size_t)row * H + lk + i] = res;
                    if (last)
                        out[(size_t)NROW * H + (row / SEQ) * H + lk + i] = res;
                }
            }
        }
        __syncthreads();

        if (l == 0) {   // re-zero upd for layer 1's atomicAdd accumulation
            for (int idx = tid; idx < 64 * 17; idx += 512)
                *(f32x4*)&upd[idx * 4] = (f32x4){0.f, 0.f, 0.f, 0.f};
            __syncthreads();
        }
    }
}

extern "C" void kernel_launch(void* const* d_in, const int* in_sizes, int n_in,
                              void* d_out, int out_size, void* d_ws, size_t ws_size,
                              hipStream_t stream) {
    const float* x    = (const float*)d_in[0];
    const float* wih0 = (const float*)d_in[1];
    const float* whh0 = (const float*)d_in[2];
    const float* bih0 = (const float*)d_in[3];
    const float* bhh0 = (const float*)d_in[4];
    const float* wih1 = (const float*)d_in[5];
    const float* whh1 = (const float*)d_in[6];
    const float* bih1 = (const float*)d_in[7];
    const float* bhh1 = (const float*)d_in[8];
    const float* coeffs = (const float*)d_in[9];
    const float* ln1g = (const float*)d_in[10];
    const float* ln1b = (const float*)d_in[11];
    const float* w1   = (const float*)d_in[12];
    const float* b1   = (const float*)d_in[13];
    const float* w2   = (const float*)d_in[14];
    const float* b2   = (const float*)d_in[15];
    const float* ln2g = (const float*)d_in[16];
    const float* ln2b = (const float*)d_in[17];

    float* out = (float*)d_out;
    float* ws  = (float*)d_ws;
    float* xpT = ws;                               // 16000*192 = 3,072,000 floats
    float* wtp = ws + (size_t)NROW * GDIM;         // 24,576 floats (k-major W^T)
    short* bfa = (short*)(wtp + GDIM * DM);        // bf16 fragment area
    float* hbuf = out;                             // reuse first 1,024,000 floats of d_out

    // one fused pack launch: 24576 + 2*(153600+8192+8192) = 364544 = 1424*256
    pack_all<<<1424, 256, 0, stream>>>(wih0, coeffs, w1, w2, wtp, bfa);
    xp0_gemm<<<NROW / 64, 256, 0, stream>>>(x, wtp, bih0, xpT);
    gru_fused<<<BSZ, 768, 0, stream>>>(xpT, whh0, bhh0, wih1, bih1, whh1, bhh1, hbuf);
    sindy_fused<<<NROW / 64, 512, 0, stream>>>(hbuf, bfa, ln1g, ln1b, b1, b2,
                                               ln2g, ln2b, out);
}